// Round 1
// baseline (921.841 us; speedup 1.0000x reference)
//
#include <hip/hip_runtime.h>
#include <hip/hip_bf16.h>
#include <stdint.h>

// SparseMoE: B=8,S=2048 -> 16384 tokens, D=512, E=10, H=2048, top-2.
// Sparse expert-grouped two-pass bf16 MFMA GEMM. Router in fp32.

#define N_TOK 16384
#define DIM 512
#define NEXP 10
#define HID 2048
#define BM 128
#define BN 128
#define BK 64
#define MAXSLOT (2*N_TOK + NEXP*BM)   // 34048 (each expert padded to 128)
#define NMB (MAXSLOT/BM)              // 266

typedef __attribute__((ext_vector_type(8))) short bf16x8;   // 8 bf16 = 4 VGPR
typedef __attribute__((ext_vector_type(4))) float f32x4;

__device__ __forceinline__ unsigned short f2bf(float v) {
  __hip_bfloat16 h = __float2bfloat16(v);
  return *reinterpret_cast<unsigned short*>(&h);
}

__device__ __forceinline__ void gload_lds16(const void* g, void* l) {
  __builtin_amdgcn_global_load_lds(
      (__attribute__((address_space(1))) void*)g,
      (__attribute__((address_space(3))) void*)l, 16, 0, 0);
}

// ---------------- prepack ----------------
__global__ void k_cvt_x(const float* __restrict__ x, unsigned short* __restrict__ xb) {
  size_t i = (size_t)blockIdx.x * 256 + threadIdx.x;   // one per 8 elements
  const float4* xp = (const float4*)x;
  float4 a = xp[2*i], b = xp[2*i+1];
  union { unsigned short us[8]; uint4 u4; } p;
  p.us[0]=f2bf(a.x); p.us[1]=f2bf(a.y); p.us[2]=f2bf(a.z); p.us[3]=f2bf(a.w);
  p.us[4]=f2bf(b.x); p.us[5]=f2bf(b.y); p.us[6]=f2bf(b.z); p.us[7]=f2bf(b.w);
  ((uint4*)xb)[i] = p.u4;
}

__global__ void k_cvt_router_w(const float* __restrict__ Wr, const float* __restrict__ Wn,
                               float* __restrict__ wrt, float* __restrict__ wnt) {
  int i = blockIdx.x * 256 + threadIdx.x;
  if (i < NEXP*DIM) {
    int e = i / DIM, d = i % DIM;
    wrt[i] = Wr[d*NEXP + e];
    wnt[i] = Wn[d*NEXP + e];
  }
}

// in [E][R][C] f32 -> out [E][C][R] bf16 (LDS-tiled 64x64 transpose)
__global__ void k_transpose(const float* __restrict__ in, unsigned short* __restrict__ outp,
                            int R, int C) {
  __shared__ float tile[64][65];
  int nTR = R >> 6, nTC = C >> 6;
  int b = blockIdx.x;
  int tilesPerE = nTR * nTC;
  int e = b / tilesPerE;
  int t = b % tilesPerE;
  int rb = t / nTC, cb = t % nTC;
  int tr = threadIdx.x >> 6, tc = threadIdx.x & 63;
  const float* ip = in + ((size_t)e*R + (size_t)rb*64) * C + cb*64;
  #pragma unroll
  for (int p = 0; p < 16; ++p)
    tile[p*4 + tr][tc] = ip[(size_t)(p*4 + tr)*C + tc];
  __syncthreads();
  unsigned short* op = outp + ((size_t)e*C + (size_t)cb*64) * R + rb*64;
  #pragma unroll
  for (int p = 0; p < 16; ++p)
    op[(size_t)(p*4 + tr)*R + tc] = f2bf(tile[tc][p*4 + tr]);
}

// ---------------- router (fp32 exact-ish) ----------------
__global__ __launch_bounds__(256) void k_router(
    const float* __restrict__ x, const float* __restrict__ noise,
    const float* __restrict__ wrt, const float* __restrict__ wnt,
    const float* __restrict__ br, const float* __restrict__ bnb,
    int* __restrict__ top_idx, float* __restrict__ top_gate, int* __restrict__ counts) {
  int wid = threadIdx.x >> 6, lane = threadIdx.x & 63;
  int tok = blockIdx.x * 4 + wid;
  const float4* xr = (const float4*)(x + (size_t)tok * DIM);
  float4 x0 = xr[lane*2], x1 = xr[lane*2 + 1];
  float lr[NEXP], ln[NEXP];
  #pragma unroll
  for (int e = 0; e < NEXP; ++e) {
    const float4* a4 = (const float4*)(wrt + e*DIM);
    const float4* c4 = (const float4*)(wnt + e*DIM);
    float4 a = a4[lane*2], b = a4[lane*2+1];
    float4 c = c4[lane*2], d = c4[lane*2+1];
    lr[e] = x0.x*a.x + x0.y*a.y + x0.z*a.z + x0.w*a.w
          + x1.x*b.x + x1.y*b.y + x1.z*b.z + x1.w*b.w;
    ln[e] = x0.x*c.x + x0.y*c.y + x0.z*c.z + x0.w*c.w
          + x1.x*d.x + x1.y*d.y + x1.z*d.z + x1.w*d.w;
  }
  #pragma unroll
  for (int off = 32; off > 0; off >>= 1) {
    #pragma unroll
    for (int e = 0; e < NEXP; ++e) {
      lr[e] += __shfl_xor(lr[e], off);
      ln[e] += __shfl_xor(ln[e], off);
    }
  }
  if (lane == 0) {
    float v[NEXP];
    #pragma unroll
    for (int e = 0; e < NEXP; ++e) {
      float nl = ln[e] + bnb[e];
      float sp = (nl > 20.f) ? nl : log1pf(expf(nl));   // softplus
      v[e] = lr[e] + br[e] + noise[(size_t)tok*NEXP + e] * sp;
    }
    float v0 = -1e30f, v1 = -1e30f; int i0 = 0, i1 = 0;
    #pragma unroll
    for (int e = 0; e < NEXP; ++e) {
      if (v[e] > v0) { v1 = v0; i1 = i0; v0 = v[e]; i0 = e; }
      else if (v[e] > v1) { v1 = v[e]; i1 = e; }
    }
    float ev = expf(v1 - v0);                 // top-2 softmax, v0 >= v1
    float g0 = 1.f / (1.f + ev);
    float g1 = ev / (1.f + ev);
    top_idx[tok*2] = i0; top_idx[tok*2+1] = i1;
    top_gate[tok*2] = g0; top_gate[tok*2+1] = g1;
    atomicAdd(&counts[i0], 1);
    atomicAdd(&counts[i1], 1);
  }
}

__global__ void k_offsets(const int* __restrict__ counts, int* __restrict__ cursors,
                          int* __restrict__ offs) {
  if (threadIdx.x == 0 && blockIdx.x == 0) {
    int acc = 0;
    for (int e = 0; e < NEXP; ++e) {
      offs[e] = acc; cursors[e] = acc;
      acc += ((counts[e] + BM - 1) / BM) * BM;   // pad to BM so blocks never straddle experts
    }
    offs[NEXP] = acc;
  }
}

__global__ void k_scatter(const int* __restrict__ top_idx, const float* __restrict__ top_gate,
                          int* __restrict__ cursors, int* __restrict__ slot_token,
                          float* __restrict__ slot_gate) {
  int t = blockIdx.x * 256 + threadIdx.x;
  if (t < N_TOK) {
    #pragma unroll
    for (int k = 0; k < 2; ++k) {
      int e = top_idx[t*2 + k];
      int pos = atomicAdd(&cursors[e], 1);
      slot_token[pos] = t;
      slot_gate[pos] = top_gate[t*2 + k];
    }
  }
}

// ---------------- GEMM1: h = relu(gather(x) @ W1[e] + b1[e]) ----------------
__global__ __launch_bounds__(256) void k_gemm1(
    const unsigned short* __restrict__ xb, const unsigned short* __restrict__ w1t,
    const float* __restrict__ b1, const int* __restrict__ slot_token,
    const int* __restrict__ offs, unsigned short* __restrict__ h) {
  __shared__ unsigned short As[BM*BK];
  __shared__ unsigned short Bs[BN*BK];
  int bm = blockIdx.x, bn = blockIdx.y;
  int tid = threadIdx.x, wid = tid >> 6, lane = tid & 63;
  int s0 = bm * BM;
  int e = 0;
  #pragma unroll
  for (int i = 1; i < NEXP; ++i) if (s0 >= offs[i]) e = i;

  int tokA[4];
  #pragma unroll
  for (int i = 0; i < 4; ++i) {
    int r = (i*4 + wid)*8 + (lane >> 3);
    int t = slot_token[s0 + r];
    tokA[i] = t < 0 ? 0 : t;
  }
  int kc = (lane & 7) * 8;
  const unsigned short* w1te = w1t + ((size_t)e*HID + (size_t)bn*BN) * DIM;

  f32x4 acc[4][4];
  #pragma unroll
  for (int m=0;m<4;m++)
    #pragma unroll
    for (int n=0;n<4;n++) acc[m][n] = (f32x4){0.f,0.f,0.f,0.f};

  int wr = wid >> 1, wc = wid & 1;

  for (int kt = 0; kt < DIM/BK; ++kt) {
    int k0 = kt * BK;
    #pragma unroll
    for (int i = 0; i < 4; ++i) {
      int r = (i*4 + wid)*8 + (lane >> 3);
      gload_lds16(xb + (size_t)tokA[i]*DIM + k0 + kc, &As[r*BK + kc]);
      gload_lds16(w1te + (size_t)r*DIM + k0 + kc, &Bs[r*BK + kc]);
    }
    __syncthreads();
    #pragma unroll
    for (int ks = 0; ks < 2; ++ks) {
      int kk = ks*32 + (lane >> 4)*8;
      bf16x8 a[4], b[4];
      #pragma unroll
      for (int m=0;m<4;m++) a[m] = *(const bf16x8*)&As[(wr*64 + m*16 + (lane&15))*BK + kk];
      #pragma unroll
      for (int n=0;n<4;n++) b[n] = *(const bf16x8*)&Bs[(wc*64 + n*16 + (lane&15))*BK + kk];
      #pragma unroll
      for (int m=0;m<4;m++)
        #pragma unroll
        for (int n=0;n<4;n++)
          acc[m][n] = __builtin_amdgcn_mfma_f32_16x16x32_bf16(a[m], b[n], acc[m][n], 0,0,0);
    }
    __syncthreads();
  }
  #pragma unroll
  for (int m=0;m<4;m++){
    int row0 = wr*64 + m*16 + (lane>>4)*4;
    #pragma unroll
    for (int n=0;n<4;n++){
      int col = bn*BN + wc*64 + n*16 + (lane&15);
      float bias = b1[e*HID + col];
      #pragma unroll
      for (int r=0;r<4;r++){
        float v = acc[m][n][r] + bias;
        v = v > 0.f ? v : 0.f;
        h[(size_t)(s0 + row0 + r)*HID + col] = f2bf(v);
      }
    }
  }
}

// ---------------- GEMM2: out[tok] += gate * (h @ W2[e] + b2[e]) ----------------
__global__ __launch_bounds__(256) void k_gemm2(
    const unsigned short* __restrict__ h, const unsigned short* __restrict__ w2t,
    const float* __restrict__ b2, const int* __restrict__ slot_token,
    const float* __restrict__ slot_gate, const int* __restrict__ offs,
    float* __restrict__ out) {
  __shared__ unsigned short As[BM*BK];
  __shared__ unsigned short Bs[BN*BK];
  int bm = blockIdx.x, bn = blockIdx.y;
  int tid = threadIdx.x, wid = tid >> 6, lane = tid & 63;
  int s0 = bm * BM;
  int e = 0;
  #pragma unroll
  for (int i = 1; i < NEXP; ++i) if (s0 >= offs[i]) e = i;
  int kc = (lane & 7) * 8;
  const unsigned short* w2te = w2t + ((size_t)e*DIM + (size_t)bn*BN) * HID;

  f32x4 acc[4][4];
  #pragma unroll
  for (int m=0;m<4;m++)
    #pragma unroll
    for (int n=0;n<4;n++) acc[m][n] = (f32x4){0.f,0.f,0.f,0.f};

  int wr = wid >> 1, wc = wid & 1;

  for (int kt = 0; kt < HID/BK; ++kt) {
    int k0 = kt * BK;
    #pragma unroll
    for (int i = 0; i < 4; ++i) {
      int r = (i*4 + wid)*8 + (lane >> 3);
      gload_lds16(h + (size_t)(s0 + r)*HID + k0 + kc, &As[r*BK + kc]);
      gload_lds16(w2te + (size_t)r*HID + k0 + kc, &Bs[r*BK + kc]);
    }
    __syncthreads();
    #pragma unroll
    for (int ks = 0; ks < 2; ++ks) {
      int kk = ks*32 + (lane >> 4)*8;
      bf16x8 a[4], b[4];
      #pragma unroll
      for (int m=0;m<4;m++) a[m] = *(const bf16x8*)&As[(wr*64 + m*16 + (lane&15))*BK + kk];
      #pragma unroll
      for (int n=0;n<4;n++) b[n] = *(const bf16x8*)&Bs[(wc*64 + n*16 + (lane&15))*BK + kk];
      #pragma unroll
      for (int m=0;m<4;m++)
        #pragma unroll
        for (int n=0;n<4;n++)
          acc[m][n] = __builtin_amdgcn_mfma_f32_16x16x32_bf16(a[m], b[n], acc[m][n], 0,0,0);
    }
    __syncthreads();
  }
  #pragma unroll
  for (int m=0;m<4;m++){
    int rb_ = s0 + wr*64 + m*16 + (lane>>4)*4;
    #pragma unroll
    for (int r=0;r<4;r++){
      int slot = rb_ + r;
      int tok = slot_token[slot];
      if (tok < 0) continue;
      float g = slot_gate[slot];
      #pragma unroll
      for (int n=0;n<4;n++){
        int col = bn*BN + wc*64 + n*16 + (lane&15);
        float v = (acc[m][n][r] + b2[e*DIM + col]) * g;
        atomicAdd(&out[(size_t)tok*DIM + col], v);  // exactly 2 adds/elem -> deterministic
      }
    }
  }
}

extern "C" void kernel_launch(void* const* d_in, const int* in_sizes, int n_in,
                              void* d_out, int out_size, void* d_ws, size_t ws_size,
                              hipStream_t stream) {
  const float* x   = (const float*)d_in[0];
  const float* noi = (const float*)d_in[1];
  const float* Wr  = (const float*)d_in[2];
  const float* br  = (const float*)d_in[3];
  const float* Wn  = (const float*)d_in[4];
  const float* bnb = (const float*)d_in[5];
  const float* W1  = (const float*)d_in[6];
  const float* b1  = (const float*)d_in[7];
  const float* W2  = (const float*)d_in[8];
  const float* b2  = (const float*)d_in[9];
  float* out = (float*)d_out;
  (void)in_sizes; (void)n_in; (void)ws_size;

  char* ws = (char*)d_ws;
  size_t off = 0;
  auto alloc = [&](size_t bytes) -> void* {
    void* p = ws + off; off += (bytes + 255) & ~(size_t)255; return p;
  };
  // ~199 MB total workspace
  unsigned short* w1t  = (unsigned short*)alloc((size_t)NEXP*HID*DIM*2);
  unsigned short* w2t  = (unsigned short*)alloc((size_t)NEXP*DIM*HID*2);
  unsigned short* xb   = (unsigned short*)alloc((size_t)N_TOK*DIM*2);
  unsigned short* hbuf = (unsigned short*)alloc((size_t)MAXSLOT*HID*2);
  float* wrt = (float*)alloc(NEXP*DIM*4);
  float* wnt = (float*)alloc(NEXP*DIM*4);
  int*   top_idx  = (int*)alloc(N_TOK*2*4);
  float* top_gate = (float*)alloc(N_TOK*2*4);
  int*   slot_token = (int*)alloc((size_t)MAXSLOT*4);
  float* slot_gate  = (float*)alloc((size_t)MAXSLOT*4);
  int*   ctrl = (int*)alloc(64*4);
  int* counts  = ctrl;        // [10]
  int* cursors = ctrl + 10;   // [10]
  int* offs    = ctrl + 20;   // [11]

  hipMemsetAsync(out, 0, (size_t)out_size*4, stream);
  hipMemsetAsync(ctrl, 0, 64*4, stream);
  hipMemsetAsync(slot_token, 0xFF, (size_t)MAXSLOT*4, stream);  // -1 fill

  k_cvt_x<<<(N_TOK*DIM/8)/256, 256, 0, stream>>>(x, xb);
  k_cvt_router_w<<<(NEXP*DIM+255)/256, 256, 0, stream>>>(Wr, Wn, wrt, wnt);
  k_transpose<<<NEXP*(DIM/64)*(HID/64), 256, 0, stream>>>(W1, w1t, DIM, HID);
  k_transpose<<<NEXP*(HID/64)*(DIM/64), 256, 0, stream>>>(W2, w2t, HID, DIM);
  k_router<<<N_TOK/4, 256, 0, stream>>>(x, noi, wrt, wnt, br, bnb, top_idx, top_gate, counts);
  k_offsets<<<1, 64, 0, stream>>>(counts, cursors, offs);
  k_scatter<<<(N_TOK+255)/256, 256, 0, stream>>>(top_idx, top_gate, cursors, slot_token, slot_gate);
  k_gemm1<<<dim3(NMB, HID/BN), 256, 0, stream>>>(xb, w1t, b1, slot_token, offs, hbuf);
  k_gemm2<<<dim3(NMB, DIM/BN), 256, 0, stream>>>(hbuf, w2t, b2, slot_token, slot_gate, offs, out);
}

// Round 2
// 667.471 us; speedup vs baseline: 1.3811x; 1.3811x over previous
//
#include <hip/hip_runtime.h>
#include <hip/hip_bf16.h>
#include <stdint.h>

// SparseMoE: B=8,S=2048 -> 16384 tokens, D=512, E=10, H=2048, top-2.
// Sparse expert-grouped two-pass bf16 MFMA GEMM. Router in fp32 (no shuffles).

#define N_TOK 16384
#define DIM 512
#define NEXP 10
#define HID 2048
#define BM 128
#define BN 128
#define BK 64
#define MAXSLOT (2*N_TOK + NEXP*BM)   // 34048 (each expert padded to 128)
#define NMB (MAXSLOT/BM)              // 266
#define RT_TOK 32                     // router tokens per block

typedef __attribute__((ext_vector_type(8))) short bf16x8;   // 8 bf16 = 4 VGPR
typedef __attribute__((ext_vector_type(4))) float f32x4;

__device__ __forceinline__ unsigned short f2bf(float v) {
  __hip_bfloat16 h = __float2bfloat16(v);
  return *reinterpret_cast<unsigned short*>(&h);
}

__device__ __forceinline__ void gload_lds16(const void* g, void* l) {
  __builtin_amdgcn_global_load_lds(
      (__attribute__((address_space(1))) void*)g,
      (__attribute__((address_space(3))) void*)l, 16, 0, 0);
}

// ---------------- prepack ----------------
__global__ void k_cvt_x(const float* __restrict__ x, unsigned short* __restrict__ xb) {
  size_t i = (size_t)blockIdx.x * 256 + threadIdx.x;   // one per 8 elements
  const float4* xp = (const float4*)x;
  float4 a = xp[2*i], b = xp[2*i+1];
  union { unsigned short us[8]; uint4 u4; } p;
  p.us[0]=f2bf(a.x); p.us[1]=f2bf(a.y); p.us[2]=f2bf(a.z); p.us[3]=f2bf(a.w);
  p.us[4]=f2bf(b.x); p.us[5]=f2bf(b.y); p.us[6]=f2bf(b.z); p.us[7]=f2bf(b.w);
  ((uint4*)xb)[i] = p.u4;
}

__global__ void k_cvt_router_w(const float* __restrict__ Wr, const float* __restrict__ Wn,
                               float* __restrict__ wrt, float* __restrict__ wnt) {
  int i = blockIdx.x * 256 + threadIdx.x;
  if (i < NEXP*DIM) {
    int e = i / DIM, d = i % DIM;
    wrt[i] = Wr[d*NEXP + e];
    wnt[i] = Wn[d*NEXP + e];
  }
}

// in [E][R][C] f32 -> out [E][C][R] bf16 (LDS-tiled 64x64 transpose)
__global__ void k_transpose(const float* __restrict__ in, unsigned short* __restrict__ outp,
                            int R, int C) {
  __shared__ float tile[64][65];
  int nTR = R >> 6, nTC = C >> 6;
  int b = blockIdx.x;
  int tilesPerE = nTR * nTC;
  int e = b / tilesPerE;
  int t = b % tilesPerE;
  int rb = t / nTC, cb = t % nTC;
  int tr = threadIdx.x >> 6, tc = threadIdx.x & 63;
  const float* ip = in + ((size_t)e*R + (size_t)rb*64) * C + cb*64;
  #pragma unroll
  for (int p = 0; p < 16; ++p)
    tile[p*4 + tr][tc] = ip[(size_t)(p*4 + tr)*C + tc];
  __syncthreads();
  unsigned short* op = outp + ((size_t)e*C + (size_t)cb*64) * R + rb*64;
  #pragma unroll
  for (int p = 0; p < 16; ++p)
    op[(size_t)(p*4 + tr)*R + tc] = f2bf(tile[tc][p*4 + tr]);
}

// ---------------- router (fp32, shuffle-free) ----------------
// 256 threads = 32 tokens x 8 d-groups; each thread owns 64 d of all 20 dots.
__global__ __launch_bounds__(256) void k_router2(
    const float* __restrict__ x, const float* __restrict__ noise,
    const float* __restrict__ wrt, const float* __restrict__ wnt,
    const float* __restrict__ br, const float* __restrict__ bnb,
    int* __restrict__ top_idx, float* __restrict__ top_gate, int* __restrict__ counts) {
  __shared__ float part[8][RT_TOK][21];   // padded: stride 21 -> conflict-free
  __shared__ float red[RT_TOK][21];
  __shared__ float vsh[RT_TOK][10];
  int tid = threadIdx.x;
  int tl = tid & 31;          // token-local
  int g  = tid >> 5;          // d-group 0..7
  int tok = blockIdx.x * RT_TOK + tl;

  const float4* xr = (const float4*)(x + (size_t)tok*DIM + g*64);
  float acc[20];
  #pragma unroll
  for (int j = 0; j < 20; ++j) acc[j] = 0.f;

  #pragma unroll 4
  for (int c = 0; c < 16; ++c) {
    float4 xv = xr[c];
    int d = g*64 + c*4;
    #pragma unroll
    for (int e = 0; e < NEXP; ++e) {
      float4 a = *(const float4*)(wrt + e*DIM + d);
      float4 b = *(const float4*)(wnt + e*DIM + d);
      acc[e]      += xv.x*a.x + xv.y*a.y + xv.z*a.z + xv.w*a.w;
      acc[10+e]   += xv.x*b.x + xv.y*b.y + xv.z*b.z + xv.w*b.w;
    }
  }
  #pragma unroll
  for (int j = 0; j < 20; ++j) part[g][tl][j] = acc[j];
  __syncthreads();

  // 8-way partial reduce: 640 outputs over 256 threads
  for (int o = tid; o < RT_TOK*20; o += 256) {
    int t2 = o / 20, j = o % 20;
    float s = 0.f;
    #pragma unroll
    for (int gg = 0; gg < 8; ++gg) s += part[gg][t2][j];
    red[t2][j] = s;
  }
  __syncthreads();

  // fuse bias + noise*softplus -> v
  if (tid < RT_TOK*NEXP + (256 - RT_TOK*NEXP) * 0) {}  // (no-op, keep shape clear)
  for (int o = tid; o < RT_TOK*NEXP; o += 256) {
    int t2 = o / NEXP, e = o % NEXP;
    float nl = red[t2][10+e] + bnb[e];
    float sp = (nl > 20.f) ? nl : log1pf(expf(nl));
    vsh[t2][e] = red[t2][e] + br[e]
               + noise[(size_t)(blockIdx.x*RT_TOK + t2)*NEXP + e] * sp;
  }
  __syncthreads();

  // per-token top-2 + gates (32 threads)
  if (tid < RT_TOK) {
    int t2 = tid;
    float v0 = -1e30f, v1 = -1e30f; int i0 = 0, i1 = 0;
    #pragma unroll
    for (int e = 0; e < NEXP; ++e) {
      float v = vsh[t2][e];
      if (v > v0) { v1 = v0; i1 = i0; v0 = v; i0 = e; }
      else if (v > v1) { v1 = v; i1 = e; }
    }
    float ev = expf(v1 - v0);                 // top-2 softmax, v0 >= v1
    float g0 = 1.f / (1.f + ev);
    float g1 = ev / (1.f + ev);
    int tk = blockIdx.x * RT_TOK + t2;
    top_idx[tk*2] = i0; top_idx[tk*2+1] = i1;
    top_gate[tk*2] = g0; top_gate[tk*2+1] = g1;
    atomicAdd(&counts[i0], 1);
    atomicAdd(&counts[i1], 1);
  }
}

__global__ void k_offsets(const int* __restrict__ counts, int* __restrict__ cursors,
                          int* __restrict__ offs) {
  if (threadIdx.x == 0 && blockIdx.x == 0) {
    int acc = 0;
    for (int e = 0; e < NEXP; ++e) {
      offs[e] = acc; cursors[e] = acc;
      acc += ((counts[e] + BM - 1) / BM) * BM;   // pad to BM so blocks never straddle experts
    }
    offs[NEXP] = acc;
  }
}

__global__ void k_scatter(const int* __restrict__ top_idx, const float* __restrict__ top_gate,
                          int* __restrict__ cursors, int* __restrict__ slot_token,
                          float* __restrict__ slot_gate) {
  int t = blockIdx.x * 256 + threadIdx.x;
  if (t < N_TOK) {
    #pragma unroll
    for (int k = 0; k < 2; ++k) {
      int e = top_idx[t*2 + k];
      int pos = atomicAdd(&cursors[e], 1);
      slot_token[pos] = t;
      slot_gate[pos] = top_gate[t*2 + k];
    }
  }
}

// ---------------- GEMM1: h = relu(gather(x) @ W1[e] + b1[e]) ----------------
__global__ __launch_bounds__(256) void k_gemm1(
    const unsigned short* __restrict__ xb, const unsigned short* __restrict__ w1t,
    const float* __restrict__ b1, const int* __restrict__ slot_token,
    const int* __restrict__ offs, unsigned short* __restrict__ h) {
  __shared__ unsigned short As[BM*BK];
  __shared__ unsigned short Bs[BN*BK];
  int bm = blockIdx.x, bn = blockIdx.y;
  int tid = threadIdx.x, wid = tid >> 6, lane = tid & 63;
  int s0 = bm * BM;
  int e = 0;
  #pragma unroll
  for (int i = 1; i < NEXP; ++i) if (s0 >= offs[i]) e = i;

  int tokA[4];
  #pragma unroll
  for (int i = 0; i < 4; ++i) {
    int r = (i*4 + wid)*8 + (lane >> 3);
    int t = slot_token[s0 + r];
    tokA[i] = t < 0 ? 0 : t;
  }
  int kc = (lane & 7) * 8;
  const unsigned short* w1te = w1t + ((size_t)e*HID + (size_t)bn*BN) * DIM;

  f32x4 acc[4][4];
  #pragma unroll
  for (int m=0;m<4;m++)
    #pragma unroll
    for (int n=0;n<4;n++) acc[m][n] = (f32x4){0.f,0.f,0.f,0.f};

  int wr = wid >> 1, wc = wid & 1;

  for (int kt = 0; kt < DIM/BK; ++kt) {
    int k0 = kt * BK;
    #pragma unroll
    for (int i = 0; i < 4; ++i) {
      int r = (i*4 + wid)*8 + (lane >> 3);
      gload_lds16(xb + (size_t)tokA[i]*DIM + k0 + kc, &As[r*BK + kc]);
      gload_lds16(w1te + (size_t)r*DIM + k0 + kc, &Bs[r*BK + kc]);
    }
    __syncthreads();
    #pragma unroll
    for (int ks = 0; ks < 2; ++ks) {
      int kk = ks*32 + (lane >> 4)*8;
      bf16x8 a[4], b[4];
      #pragma unroll
      for (int m=0;m<4;m++) a[m] = *(const bf16x8*)&As[(wr*64 + m*16 + (lane&15))*BK + kk];
      #pragma unroll
      for (int n=0;n<4;n++) b[n] = *(const bf16x8*)&Bs[(wc*64 + n*16 + (lane&15))*BK + kk];
      #pragma unroll
      for (int m=0;m<4;m++)
        #pragma unroll
        for (int n=0;n<4;n++)
          acc[m][n] = __builtin_amdgcn_mfma_f32_16x16x32_bf16(a[m], b[n], acc[m][n], 0,0,0);
    }
    __syncthreads();
  }
  #pragma unroll
  for (int m=0;m<4;m++){
    int row0 = wr*64 + m*16 + (lane>>4)*4;
    #pragma unroll
    for (int n=0;n<4;n++){
      int col = bn*BN + wc*64 + n*16 + (lane&15);
      float bias = b1[e*HID + col];
      #pragma unroll
      for (int r=0;r<4;r++){
        float v = acc[m][n][r] + bias;
        v = v > 0.f ? v : 0.f;
        h[(size_t)(s0 + row0 + r)*HID + col] = f2bf(v);
      }
    }
  }
}

// ---------------- GEMM2: out[tok] += gate * (h @ W2[e] + b2[e]) ----------------
__global__ __launch_bounds__(256) void k_gemm2(
    const unsigned short* __restrict__ h, const unsigned short* __restrict__ w2t,
    const float* __restrict__ b2, const int* __restrict__ slot_token,
    const float* __restrict__ slot_gate, const int* __restrict__ offs,
    float* __restrict__ out) {
  __shared__ unsigned short As[BM*BK];
  __shared__ unsigned short Bs[BN*BK];
  int bm = blockIdx.x, bn = blockIdx.y;
  int tid = threadIdx.x, wid = tid >> 6, lane = tid & 63;
  int s0 = bm * BM;
  int e = 0;
  #pragma unroll
  for (int i = 1; i < NEXP; ++i) if (s0 >= offs[i]) e = i;
  int kc = (lane & 7) * 8;
  const unsigned short* w2te = w2t + ((size_t)e*DIM + (size_t)bn*BN) * HID;

  f32x4 acc[4][4];
  #pragma unroll
  for (int m=0;m<4;m++)
    #pragma unroll
    for (int n=0;n<4;n++) acc[m][n] = (f32x4){0.f,0.f,0.f,0.f};

  int wr = wid >> 1, wc = wid & 1;

  for (int kt = 0; kt < HID/BK; ++kt) {
    int k0 = kt * BK;
    #pragma unroll
    for (int i = 0; i < 4; ++i) {
      int r = (i*4 + wid)*8 + (lane >> 3);
      gload_lds16(h + (size_t)(s0 + r)*HID + k0 + kc, &As[r*BK + kc]);
      gload_lds16(w2te + (size_t)r*HID + k0 + kc, &Bs[r*BK + kc]);
    }
    __syncthreads();
    #pragma unroll
    for (int ks = 0; ks < 2; ++ks) {
      int kk = ks*32 + (lane >> 4)*8;
      bf16x8 a[4], b[4];
      #pragma unroll
      for (int m=0;m<4;m++) a[m] = *(const bf16x8*)&As[(wr*64 + m*16 + (lane&15))*BK + kk];
      #pragma unroll
      for (int n=0;n<4;n++) b[n] = *(const bf16x8*)&Bs[(wc*64 + n*16 + (lane&15))*BK + kk];
      #pragma unroll
      for (int m=0;m<4;m++)
        #pragma unroll
        for (int n=0;n<4;n++)
          acc[m][n] = __builtin_amdgcn_mfma_f32_16x16x32_bf16(a[m], b[n], acc[m][n], 0,0,0);
    }
    __syncthreads();
  }
  #pragma unroll
  for (int m=0;m<4;m++){
    int rb_ = s0 + wr*64 + m*16 + (lane>>4)*4;
    #pragma unroll
    for (int r=0;r<4;r++){
      int slot = rb_ + r;
      int tok = slot_token[slot];
      if (tok < 0) continue;
      float g = slot_gate[slot];
      #pragma unroll
      for (int n=0;n<4;n++){
        int col = bn*BN + wc*64 + n*16 + (lane&15);
        float v = (acc[m][n][r] + b2[e*DIM + col]) * g;
        atomicAdd(&out[(size_t)tok*DIM + col], v);  // exactly 2 adds/elem -> deterministic
      }
    }
  }
}

extern "C" void kernel_launch(void* const* d_in, const int* in_sizes, int n_in,
                              void* d_out, int out_size, void* d_ws, size_t ws_size,
                              hipStream_t stream) {
  const float* x   = (const float*)d_in[0];
  const float* noi = (const float*)d_in[1];
  const float* Wr  = (const float*)d_in[2];
  const float* br  = (const float*)d_in[3];
  const float* Wn  = (const float*)d_in[4];
  const float* bnb = (const float*)d_in[5];
  const float* W1  = (const float*)d_in[6];
  const float* b1  = (const float*)d_in[7];
  const float* W2  = (const float*)d_in[8];
  const float* b2  = (const float*)d_in[9];
  float* out = (float*)d_out;
  (void)in_sizes; (void)n_in; (void)ws_size;

  char* ws = (char*)d_ws;
  size_t off = 0;
  auto alloc = [&](size_t bytes) -> void* {
    void* p = ws + off; off += (bytes + 255) & ~(size_t)255; return p;
  };
  // ~199 MB total workspace
  unsigned short* w1t  = (unsigned short*)alloc((size_t)NEXP*HID*DIM*2);
  unsigned short* w2t  = (unsigned short*)alloc((size_t)NEXP*DIM*HID*2);
  unsigned short* xb   = (unsigned short*)alloc((size_t)N_TOK*DIM*2);
  unsigned short* hbuf = (unsigned short*)alloc((size_t)MAXSLOT*HID*2);
  float* wrt = (float*)alloc(NEXP*DIM*4);
  float* wnt = (float*)alloc(NEXP*DIM*4);
  int*   top_idx  = (int*)alloc(N_TOK*2*4);
  float* top_gate = (float*)alloc(N_TOK*2*4);
  int*   slot_token = (int*)alloc((size_t)MAXSLOT*4);
  float* slot_gate  = (float*)alloc((size_t)MAXSLOT*4);
  int*   ctrl = (int*)alloc(64*4);
  int* counts  = ctrl;        // [10]
  int* cursors = ctrl + 10;   // [10]
  int* offs    = ctrl + 20;   // [11]

  hipMemsetAsync(out, 0, (size_t)out_size*4, stream);
  hipMemsetAsync(ctrl, 0, 64*4, stream);
  hipMemsetAsync(slot_token, 0xFF, (size_t)MAXSLOT*4, stream);  // -1 fill

  k_cvt_x<<<(N_TOK*DIM/8)/256, 256, 0, stream>>>(x, xb);
  k_cvt_router_w<<<(NEXP*DIM+255)/256, 256, 0, stream>>>(Wr, Wn, wrt, wnt);
  k_transpose<<<NEXP*(DIM/64)*(HID/64), 256, 0, stream>>>(W1, w1t, DIM, HID);
  k_transpose<<<NEXP*(HID/64)*(DIM/64), 256, 0, stream>>>(W2, w2t, HID, DIM);
  k_router2<<<N_TOK/RT_TOK, 256, 0, stream>>>(x, noi, wrt, wnt, br, bnb, top_idx, top_gate, counts);
  k_offsets<<<1, 64, 0, stream>>>(counts, cursors, offs);
  k_scatter<<<(N_TOK+255)/256, 256, 0, stream>>>(top_idx, top_gate, cursors, slot_token, slot_gate);
  k_gemm1<<<dim3(NMB, HID/BN), 256, 0, stream>>>(xb, w1t, b1, slot_token, offs, hbuf);
  k_gemm2<<<dim3(NMB, DIM/BN), 256, 0, stream>>>(hbuf, w2t, b2, slot_token, slot_gate, offs, out);
}

// Round 3
// 659.695 us; speedup vs baseline: 1.3974x; 1.0118x over previous
//
#include <hip/hip_runtime.h>
#include <hip/hip_bf16.h>
#include <stdint.h>

// SparseMoE: B=8,S=2048 -> 16384 tokens, D=512, E=10, H=2048, top-2.
// Sparse expert-grouped two-pass bf16 MFMA GEMM. Router in fp32 (no shuffles).
// R2: chunked-XCD block swizzle (T1) so bn-siblings sharing an A-panel and
// bm-runs sharing an expert weight panel land on the SAME XCD's L2.

#define N_TOK 16384
#define DIM 512
#define NEXP 10
#define HID 2048
#define BM 128
#define BN 128
#define BK 64
#define MAXSLOT (2*N_TOK + NEXP*BM)   // 34048 (each expert padded to 128)
#define NMB (MAXSLOT/BM)              // 266
#define RT_TOK 32                     // router tokens per block
#define NBN1 (HID/BN)                 // 16
#define NBN2 (DIM/BN)                 // 4

typedef __attribute__((ext_vector_type(8))) short bf16x8;   // 8 bf16 = 4 VGPR
typedef __attribute__((ext_vector_type(4))) float f32x4;

__device__ __forceinline__ unsigned short f2bf(float v) {
  __hip_bfloat16 h = __float2bfloat16(v);
  return *reinterpret_cast<unsigned short*>(&h);
}

__device__ __forceinline__ void gload_lds16(const void* g, void* l) {
  __builtin_amdgcn_global_load_lds(
      (__attribute__((address_space(1))) void*)g,
      (__attribute__((address_space(3))) void*)l, 16, 0, 0);
}

// bijective chunked XCD remap (m204): blocks b, b+... with consecutive w on same XCD
__device__ __forceinline__ int xcd_chunk(int b, int nwg) {
  int q = nwg >> 3, r = nwg & 7;
  int xcd = b & 7, slot = b >> 3;
  return (xcd < r) ? (xcd*(q+1) + slot) : (r*(q+1) + (xcd-r)*q + slot);
}

// ---------------- prepack ----------------
__global__ void k_cvt_x(const float* __restrict__ x, unsigned short* __restrict__ xb) {
  size_t i = (size_t)blockIdx.x * 256 + threadIdx.x;   // one per 8 elements
  const float4* xp = (const float4*)x;
  float4 a = xp[2*i], b = xp[2*i+1];
  union { unsigned short us[8]; uint4 u4; } p;
  p.us[0]=f2bf(a.x); p.us[1]=f2bf(a.y); p.us[2]=f2bf(a.z); p.us[3]=f2bf(a.w);
  p.us[4]=f2bf(b.x); p.us[5]=f2bf(b.y); p.us[6]=f2bf(b.z); p.us[7]=f2bf(b.w);
  ((uint4*)xb)[i] = p.u4;
}

__global__ void k_cvt_router_w(const float* __restrict__ Wr, const float* __restrict__ Wn,
                               float* __restrict__ wrt, float* __restrict__ wnt) {
  int i = blockIdx.x * 256 + threadIdx.x;
  if (i < NEXP*DIM) {
    int e = i / DIM, d = i % DIM;
    wrt[i] = Wr[d*NEXP + e];
    wnt[i] = Wn[d*NEXP + e];
  }
}

// in [E][R][C] f32 -> out [E][C][R] bf16 (LDS-tiled 64x64 transpose)
__global__ void k_transpose(const float* __restrict__ in, unsigned short* __restrict__ outp,
                            int R, int C) {
  __shared__ float tile[64][65];
  int nTR = R >> 6, nTC = C >> 6;
  int b = blockIdx.x;
  int tilesPerE = nTR * nTC;
  int e = b / tilesPerE;
  int t = b % tilesPerE;
  int rb = t / nTC, cb = t % nTC;
  int tr = threadIdx.x >> 6, tc = threadIdx.x & 63;
  const float* ip = in + ((size_t)e*R + (size_t)rb*64) * C + cb*64;
  #pragma unroll
  for (int p = 0; p < 16; ++p)
    tile[p*4 + tr][tc] = ip[(size_t)(p*4 + tr)*C + tc];
  __syncthreads();
  unsigned short* op = outp + ((size_t)e*C + (size_t)cb*64) * R + rb*64;
  #pragma unroll
  for (int p = 0; p < 16; ++p)
    op[(size_t)(p*4 + tr)*R + tc] = f2bf(tile[tc][p*4 + tr]);
}

// ---------------- router (fp32, shuffle-free) ----------------
// 256 threads = 32 tokens x 8 d-groups; each thread owns 64 d of all 20 dots.
__global__ __launch_bounds__(256) void k_router2(
    const float* __restrict__ x, const float* __restrict__ noise,
    const float* __restrict__ wrt, const float* __restrict__ wnt,
    const float* __restrict__ br, const float* __restrict__ bnb,
    int* __restrict__ top_idx, float* __restrict__ top_gate, int* __restrict__ counts) {
  __shared__ float part[8][RT_TOK][21];   // padded: stride 21 -> conflict-free
  __shared__ float red[RT_TOK][21];
  __shared__ float vsh[RT_TOK][10];
  int tid = threadIdx.x;
  int tl = tid & 31;          // token-local
  int g  = tid >> 5;          // d-group 0..7
  int tok = blockIdx.x * RT_TOK + tl;

  const float4* xr = (const float4*)(x + (size_t)tok*DIM + g*64);
  float acc[20];
  #pragma unroll
  for (int j = 0; j < 20; ++j) acc[j] = 0.f;

  #pragma unroll 4
  for (int c = 0; c < 16; ++c) {
    float4 xv = xr[c];
    int d = g*64 + c*4;
    #pragma unroll
    for (int e = 0; e < NEXP; ++e) {
      float4 a = *(const float4*)(wrt + e*DIM + d);
      float4 b = *(const float4*)(wnt + e*DIM + d);
      acc[e]      += xv.x*a.x + xv.y*a.y + xv.z*a.z + xv.w*a.w;
      acc[10+e]   += xv.x*b.x + xv.y*b.y + xv.z*b.z + xv.w*b.w;
    }
  }
  #pragma unroll
  for (int j = 0; j < 20; ++j) part[g][tl][j] = acc[j];
  __syncthreads();

  // 8-way partial reduce: 640 outputs over 256 threads
  for (int o = tid; o < RT_TOK*20; o += 256) {
    int t2 = o / 20, j = o % 20;
    float s = 0.f;
    #pragma unroll
    for (int gg = 0; gg < 8; ++gg) s += part[gg][t2][j];
    red[t2][j] = s;
  }
  __syncthreads();

  // fuse bias + noise*softplus -> v
  for (int o = tid; o < RT_TOK*NEXP; o += 256) {
    int t2 = o / NEXP, e = o % NEXP;
    float nl = red[t2][10+e] + bnb[e];
    float sp = (nl > 20.f) ? nl : log1pf(expf(nl));
    vsh[t2][e] = red[t2][e] + br[e]
               + noise[(size_t)(blockIdx.x*RT_TOK + t2)*NEXP + e] * sp;
  }
  __syncthreads();

  // per-token top-2 + gates (32 threads)
  if (tid < RT_TOK) {
    int t2 = tid;
    float v0 = -1e30f, v1 = -1e30f; int i0 = 0, i1 = 0;
    #pragma unroll
    for (int e = 0; e < NEXP; ++e) {
      float v = vsh[t2][e];
      if (v > v0) { v1 = v0; i1 = i0; v0 = v; i0 = e; }
      else if (v > v1) { v1 = v; i1 = e; }
    }
    float ev = expf(v1 - v0);                 // top-2 softmax, v0 >= v1
    float g0 = 1.f / (1.f + ev);
    float g1 = ev / (1.f + ev);
    int tk = blockIdx.x * RT_TOK + t2;
    top_idx[tk*2] = i0; top_idx[tk*2+1] = i1;
    top_gate[tk*2] = g0; top_gate[tk*2+1] = g1;
    atomicAdd(&counts[i0], 1);
    atomicAdd(&counts[i1], 1);
  }
}

__global__ void k_offsets(const int* __restrict__ counts, int* __restrict__ cursors,
                          int* __restrict__ offs) {
  if (threadIdx.x == 0 && blockIdx.x == 0) {
    int acc = 0;
    for (int e = 0; e < NEXP; ++e) {
      offs[e] = acc; cursors[e] = acc;
      acc += ((counts[e] + BM - 1) / BM) * BM;   // pad to BM so blocks never straddle experts
    }
    offs[NEXP] = acc;
  }
}

__global__ void k_scatter(const int* __restrict__ top_idx, const float* __restrict__ top_gate,
                          int* __restrict__ cursors, int* __restrict__ slot_token,
                          float* __restrict__ slot_gate) {
  int t = blockIdx.x * 256 + threadIdx.x;
  if (t < N_TOK) {
    #pragma unroll
    for (int k = 0; k < 2; ++k) {
      int e = top_idx[t*2 + k];
      int pos = atomicAdd(&cursors[e], 1);
      slot_token[pos] = t;
      slot_gate[pos] = top_gate[t*2 + k];
    }
  }
}

// ---------------- GEMM1: h = relu(gather(x) @ W1[e] + b1[e]) ----------------
__global__ __launch_bounds__(256) void k_gemm1(
    const unsigned short* __restrict__ xb, const unsigned short* __restrict__ w1t,
    const float* __restrict__ b1, const int* __restrict__ slot_token,
    const int* __restrict__ offs, unsigned short* __restrict__ h) {
  __shared__ unsigned short As[BM*BK];
  __shared__ unsigned short Bs[BN*BK];
  int w = xcd_chunk(blockIdx.x, NMB*NBN1);
  int bm = w / NBN1, bn = w % NBN1;     // bn fast: 16 bn-siblings consecutive on one XCD
  int tid = threadIdx.x, wid = tid >> 6, lane = tid & 63;
  int s0 = bm * BM;
  int e = 0;
  #pragma unroll
  for (int i = 1; i < NEXP; ++i) if (s0 >= offs[i]) e = i;

  int tokA[4];
  #pragma unroll
  for (int i = 0; i < 4; ++i) {
    int r = (i*4 + wid)*8 + (lane >> 3);
    int t = slot_token[s0 + r];
    tokA[i] = t < 0 ? 0 : t;
  }
  int kc = (lane & 7) * 8;
  const unsigned short* w1te = w1t + ((size_t)e*HID + (size_t)bn*BN) * DIM;

  f32x4 acc[4][4];
  #pragma unroll
  for (int m=0;m<4;m++)
    #pragma unroll
    for (int n=0;n<4;n++) acc[m][n] = (f32x4){0.f,0.f,0.f,0.f};

  int wr = wid >> 1, wc = wid & 1;

  for (int kt = 0; kt < DIM/BK; ++kt) {
    int k0 = kt * BK;
    #pragma unroll
    for (int i = 0; i < 4; ++i) {
      int r = (i*4 + wid)*8 + (lane >> 3);
      gload_lds16(xb + (size_t)tokA[i]*DIM + k0 + kc, &As[r*BK + kc]);
      gload_lds16(w1te + (size_t)r*DIM + k0 + kc, &Bs[r*BK + kc]);
    }
    __syncthreads();
    #pragma unroll
    for (int ks = 0; ks < 2; ++ks) {
      int kk = ks*32 + (lane >> 4)*8;
      bf16x8 a[4], b[4];
      #pragma unroll
      for (int m=0;m<4;m++) a[m] = *(const bf16x8*)&As[(wr*64 + m*16 + (lane&15))*BK + kk];
      #pragma unroll
      for (int n=0;n<4;n++) b[n] = *(const bf16x8*)&Bs[(wc*64 + n*16 + (lane&15))*BK + kk];
      #pragma unroll
      for (int m=0;m<4;m++)
        #pragma unroll
        for (int n=0;n<4;n++)
          acc[m][n] = __builtin_amdgcn_mfma_f32_16x16x32_bf16(a[m], b[n], acc[m][n], 0,0,0);
    }
    __syncthreads();
  }
  #pragma unroll
  for (int m=0;m<4;m++){
    int row0 = wr*64 + m*16 + (lane>>4)*4;
    #pragma unroll
    for (int n=0;n<4;n++){
      int col = bn*BN + wc*64 + n*16 + (lane&15);
      float bias = b1[e*HID + col];
      #pragma unroll
      for (int r=0;r<4;r++){
        float v = acc[m][n][r] + bias;
        v = v > 0.f ? v : 0.f;
        h[(size_t)(s0 + row0 + r)*HID + col] = f2bf(v);
      }
    }
  }
}

// ---------------- GEMM2: out[tok] += gate * (h @ W2[e] + b2[e]) ----------------
__global__ __launch_bounds__(256) void k_gemm2(
    const unsigned short* __restrict__ h, const unsigned short* __restrict__ w2t,
    const float* __restrict__ b2, const int* __restrict__ slot_token,
    const float* __restrict__ slot_gate, const int* __restrict__ offs,
    float* __restrict__ out) {
  __shared__ unsigned short As[BM*BK];
  __shared__ unsigned short Bs[BN*BK];
  int w = xcd_chunk(blockIdx.x, NMB*NBN2);
  int bm = w / NBN2, bn = w % NBN2;     // bn fast: 4 bn-siblings consecutive on one XCD
  int tid = threadIdx.x, wid = tid >> 6, lane = tid & 63;
  int s0 = bm * BM;
  int e = 0;
  #pragma unroll
  for (int i = 1; i < NEXP; ++i) if (s0 >= offs[i]) e = i;
  int kc = (lane & 7) * 8;
  const unsigned short* w2te = w2t + ((size_t)e*DIM + (size_t)bn*BN) * HID;

  f32x4 acc[4][4];
  #pragma unroll
  for (int m=0;m<4;m++)
    #pragma unroll
    for (int n=0;n<4;n++) acc[m][n] = (f32x4){0.f,0.f,0.f,0.f};

  int wr = wid >> 1, wc = wid & 1;

  for (int kt = 0; kt < HID/BK; ++kt) {
    int k0 = kt * BK;
    #pragma unroll
    for (int i = 0; i < 4; ++i) {
      int r = (i*4 + wid)*8 + (lane >> 3);
      gload_lds16(h + (size_t)(s0 + r)*HID + k0 + kc, &As[r*BK + kc]);
      gload_lds16(w2te + (size_t)r*HID + k0 + kc, &Bs[r*BK + kc]);
    }
    __syncthreads();
    #pragma unroll
    for (int ks = 0; ks < 2; ++ks) {
      int kk = ks*32 + (lane >> 4)*8;
      bf16x8 a[4], b[4];
      #pragma unroll
      for (int m=0;m<4;m++) a[m] = *(const bf16x8*)&As[(wr*64 + m*16 + (lane&15))*BK + kk];
      #pragma unroll
      for (int n=0;n<4;n++) b[n] = *(const bf16x8*)&Bs[(wc*64 + n*16 + (lane&15))*BK + kk];
      #pragma unroll
      for (int m=0;m<4;m++)
        #pragma unroll
        for (int n=0;n<4;n++)
          acc[m][n] = __builtin_amdgcn_mfma_f32_16x16x32_bf16(a[m], b[n], acc[m][n], 0,0,0);
    }
    __syncthreads();
  }
  #pragma unroll
  for (int m=0;m<4;m++){
    int rb_ = s0 + wr*64 + m*16 + (lane>>4)*4;
    #pragma unroll
    for (int r=0;r<4;r++){
      int slot = rb_ + r;
      int tok = slot_token[slot];
      if (tok < 0) continue;
      float g = slot_gate[slot];
      #pragma unroll
      for (int n=0;n<4;n++){
        int col = bn*BN + wc*64 + n*16 + (lane&15);
        float v = (acc[m][n][r] + b2[e*DIM + col]) * g;
        atomicAdd(&out[(size_t)tok*DIM + col], v);  // exactly 2 adds/elem -> deterministic
      }
    }
  }
}

extern "C" void kernel_launch(void* const* d_in, const int* in_sizes, int n_in,
                              void* d_out, int out_size, void* d_ws, size_t ws_size,
                              hipStream_t stream) {
  const float* x   = (const float*)d_in[0];
  const float* noi = (const float*)d_in[1];
  const float* Wr  = (const float*)d_in[2];
  const float* br  = (const float*)d_in[3];
  const float* Wn  = (const float*)d_in[4];
  const float* bnb = (const float*)d_in[5];
  const float* W1  = (const float*)d_in[6];
  const float* b1  = (const float*)d_in[7];
  const float* W2  = (const float*)d_in[8];
  const float* b2  = (const float*)d_in[9];
  float* out = (float*)d_out;
  (void)in_sizes; (void)n_in; (void)ws_size;

  char* ws = (char*)d_ws;
  size_t off = 0;
  auto alloc = [&](size_t bytes) -> void* {
    void* p = ws + off; off += (bytes + 255) & ~(size_t)255; return p;
  };
  // ~199 MB total workspace
  unsigned short* w1t  = (unsigned short*)alloc((size_t)NEXP*HID*DIM*2);
  unsigned short* w2t  = (unsigned short*)alloc((size_t)NEXP*DIM*HID*2);
  unsigned short* xb   = (unsigned short*)alloc((size_t)N_TOK*DIM*2);
  unsigned short* hbuf = (unsigned short*)alloc((size_t)MAXSLOT*HID*2);
  float* wrt = (float*)alloc(NEXP*DIM*4);
  float* wnt = (float*)alloc(NEXP*DIM*4);
  int*   top_idx  = (int*)alloc(N_TOK*2*4);
  float* top_gate = (float*)alloc(N_TOK*2*4);
  int*   slot_token = (int*)alloc((size_t)MAXSLOT*4);
  float* slot_gate  = (float*)alloc((size_t)MAXSLOT*4);
  int*   ctrl = (int*)alloc(64*4);
  int* counts  = ctrl;        // [10]
  int* cursors = ctrl + 10;   // [10]
  int* offs    = ctrl + 20;   // [11]

  hipMemsetAsync(out, 0, (size_t)out_size*4, stream);
  hipMemsetAsync(ctrl, 0, 64*4, stream);
  hipMemsetAsync(slot_token, 0xFF, (size_t)MAXSLOT*4, stream);  // -1 fill

  k_cvt_x<<<(N_TOK*DIM/8)/256, 256, 0, stream>>>(x, xb);
  k_cvt_router_w<<<(NEXP*DIM+255)/256, 256, 0, stream>>>(Wr, Wn, wrt, wnt);
  k_transpose<<<NEXP*(DIM/64)*(HID/64), 256, 0, stream>>>(W1, w1t, DIM, HID);
  k_transpose<<<NEXP*(HID/64)*(DIM/64), 256, 0, stream>>>(W2, w2t, HID, DIM);
  k_router2<<<N_TOK/RT_TOK, 256, 0, stream>>>(x, noi, wrt, wnt, br, bnb, top_idx, top_gate, counts);
  k_offsets<<<1, 64, 0, stream>>>(counts, cursors, offs);
  k_scatter<<<(N_TOK+255)/256, 256, 0, stream>>>(top_idx, top_gate, cursors, slot_token, slot_gate);
  k_gemm1<<<NMB*NBN1, 256, 0, stream>>>(xb, w1t, b1, slot_token, offs, hbuf);
  k_gemm2<<<NMB*NBN2, 256, 0, stream>>>(hbuf, w2t, b2, slot_token, slot_gate, offs, out);
}

// Round 4
// 623.993 us; speedup vs baseline: 1.4773x; 1.0572x over previous
//
#include <hip/hip_runtime.h>
#include <hip/hip_bf16.h>
#include <stdint.h>

// SparseMoE: B=8,S=2048 -> 16384 tokens, D=512, E=10, H=2048, top-2.
// Sparse expert-grouped two-pass bf16 MFMA GEMM. Router in fp32 (no shuffles).
// R2: chunked-XCD block swizzle (T1).
// R3: T2 XOR bank-swizzle (pre-swizzled global src, swizzled ds_read) +
//     T3-minimum 2-phase LDS double-buffer with raw s_barrier + vmcnt(0)
//     (no __syncthreads in K-loop -> prefetch survives the barrier).

#define N_TOK 16384
#define DIM 512
#define NEXP 10
#define HID 2048
#define BM 128
#define BN 128
#define BK 64
#define MAXSLOT (2*N_TOK + NEXP*BM)   // 34048 (each expert padded to 128)
#define NMB (MAXSLOT/BM)              // 266
#define RT_TOK 32                     // router tokens per block
#define NBN1 (HID/BN)                 // 16
#define NBN2 (DIM/BN)                 // 4

typedef __attribute__((ext_vector_type(8))) short bf16x8;   // 8 bf16 = 4 VGPR
typedef __attribute__((ext_vector_type(4))) float f32x4;

__device__ __forceinline__ unsigned short f2bf(float v) {
  __hip_bfloat16 h = __float2bfloat16(v);
  return *reinterpret_cast<unsigned short*>(&h);
}

__device__ __forceinline__ void gload_lds16(const void* g, void* l) {
  __builtin_amdgcn_global_load_lds(
      (__attribute__((address_space(1))) void*)g,
      (__attribute__((address_space(3))) void*)l, 16, 0, 0);
}

// bijective chunked XCD remap (m204)
__device__ __forceinline__ int xcd_chunk(int b, int nwg) {
  int q = nwg >> 3, r = nwg & 7;
  int xcd = b & 7, slot = b >> 3;
  return (xcd < r) ? (xcd*(q+1) + slot) : (r*(q+1) + (xcd-r)*q + slot);
}

// ---------------- prepack ----------------
__global__ void k_cvt_x(const float* __restrict__ x, unsigned short* __restrict__ xb) {
  size_t i = (size_t)blockIdx.x * 256 + threadIdx.x;   // one per 8 elements
  const float4* xp = (const float4*)x;
  float4 a = xp[2*i], b = xp[2*i+1];
  union { unsigned short us[8]; uint4 u4; } p;
  p.us[0]=f2bf(a.x); p.us[1]=f2bf(a.y); p.us[2]=f2bf(a.z); p.us[3]=f2bf(a.w);
  p.us[4]=f2bf(b.x); p.us[5]=f2bf(b.y); p.us[6]=f2bf(b.z); p.us[7]=f2bf(b.w);
  ((uint4*)xb)[i] = p.u4;
}

__global__ void k_cvt_router_w(const float* __restrict__ Wr, const float* __restrict__ Wn,
                               float* __restrict__ wrt, float* __restrict__ wnt) {
  int i = blockIdx.x * 256 + threadIdx.x;
  if (i < NEXP*DIM) {
    int e = i / DIM, d = i % DIM;
    wrt[i] = Wr[d*NEXP + e];
    wnt[i] = Wn[d*NEXP + e];
  }
}

// in [E][R][C] f32 -> out [E][C][R] bf16 (LDS-tiled 64x64 transpose)
__global__ void k_transpose(const float* __restrict__ in, unsigned short* __restrict__ outp,
                            int R, int C) {
  __shared__ float tile[64][65];
  int nTR = R >> 6, nTC = C >> 6;
  int b = blockIdx.x;
  int tilesPerE = nTR * nTC;
  int e = b / tilesPerE;
  int t = b % tilesPerE;
  int rb = t / nTC, cb = t % nTC;
  int tr = threadIdx.x >> 6, tc = threadIdx.x & 63;
  const float* ip = in + ((size_t)e*R + (size_t)rb*64) * C + cb*64;
  #pragma unroll
  for (int p = 0; p < 16; ++p)
    tile[p*4 + tr][tc] = ip[(size_t)(p*4 + tr)*C + tc];
  __syncthreads();
  unsigned short* op = outp + ((size_t)e*C + (size_t)cb*64) * R + rb*64;
  #pragma unroll
  for (int p = 0; p < 16; ++p)
    op[(size_t)(p*4 + tr)*R + tc] = f2bf(tile[tc][p*4 + tr]);
}

// ---------------- router (fp32, shuffle-free) ----------------
__global__ __launch_bounds__(256) void k_router2(
    const float* __restrict__ x, const float* __restrict__ noise,
    const float* __restrict__ wrt, const float* __restrict__ wnt,
    const float* __restrict__ br, const float* __restrict__ bnb,
    int* __restrict__ top_idx, float* __restrict__ top_gate, int* __restrict__ counts) {
  __shared__ float part[8][RT_TOK][21];
  __shared__ float red[RT_TOK][21];
  __shared__ float vsh[RT_TOK][10];
  int tid = threadIdx.x;
  int tl = tid & 31;          // token-local
  int g  = tid >> 5;          // d-group 0..7
  int tok = blockIdx.x * RT_TOK + tl;

  const float4* xr = (const float4*)(x + (size_t)tok*DIM + g*64);
  float acc[20];
  #pragma unroll
  for (int j = 0; j < 20; ++j) acc[j] = 0.f;

  #pragma unroll 4
  for (int c = 0; c < 16; ++c) {
    float4 xv = xr[c];
    int d = g*64 + c*4;
    #pragma unroll
    for (int e = 0; e < NEXP; ++e) {
      float4 a = *(const float4*)(wrt + e*DIM + d);
      float4 b = *(const float4*)(wnt + e*DIM + d);
      acc[e]      += xv.x*a.x + xv.y*a.y + xv.z*a.z + xv.w*a.w;
      acc[10+e]   += xv.x*b.x + xv.y*b.y + xv.z*b.z + xv.w*b.w;
    }
  }
  #pragma unroll
  for (int j = 0; j < 20; ++j) part[g][tl][j] = acc[j];
  __syncthreads();

  for (int o = tid; o < RT_TOK*20; o += 256) {
    int t2 = o / 20, j = o % 20;
    float s = 0.f;
    #pragma unroll
    for (int gg = 0; gg < 8; ++gg) s += part[gg][t2][j];
    red[t2][j] = s;
  }
  __syncthreads();

  for (int o = tid; o < RT_TOK*NEXP; o += 256) {
    int t2 = o / NEXP, e = o % NEXP;
    float nl = red[t2][10+e] + bnb[e];
    float sp = (nl > 20.f) ? nl : log1pf(expf(nl));
    vsh[t2][e] = red[t2][e] + br[e]
               + noise[(size_t)(blockIdx.x*RT_TOK + t2)*NEXP + e] * sp;
  }
  __syncthreads();

  if (tid < RT_TOK) {
    int t2 = tid;
    float v0 = -1e30f, v1 = -1e30f; int i0 = 0, i1 = 0;
    #pragma unroll
    for (int e = 0; e < NEXP; ++e) {
      float v = vsh[t2][e];
      if (v > v0) { v1 = v0; i1 = i0; v0 = v; i0 = e; }
      else if (v > v1) { v1 = v; i1 = e; }
    }
    float ev = expf(v1 - v0);
    float g0 = 1.f / (1.f + ev);
    float g1 = ev / (1.f + ev);
    int tk = blockIdx.x * RT_TOK + t2;
    top_idx[tk*2] = i0; top_idx[tk*2+1] = i1;
    top_gate[tk*2] = g0; top_gate[tk*2+1] = g1;
    atomicAdd(&counts[i0], 1);
    atomicAdd(&counts[i1], 1);
  }
}

__global__ void k_offsets(const int* __restrict__ counts, int* __restrict__ cursors,
                          int* __restrict__ offs) {
  if (threadIdx.x == 0 && blockIdx.x == 0) {
    int acc = 0;
    for (int e = 0; e < NEXP; ++e) {
      offs[e] = acc; cursors[e] = acc;
      acc += ((counts[e] + BM - 1) / BM) * BM;
    }
    offs[NEXP] = acc;
  }
}

__global__ void k_scatter(const int* __restrict__ top_idx, const float* __restrict__ top_gate,
                          int* __restrict__ cursors, int* __restrict__ slot_token,
                          float* __restrict__ slot_gate) {
  int t = blockIdx.x * 256 + threadIdx.x;
  if (t < N_TOK) {
    #pragma unroll
    for (int k = 0; k < 2; ++k) {
      int e = top_idx[t*2 + k];
      int pos = atomicAdd(&cursors[e], 1);
      slot_token[pos] = t;
      slot_gate[pos] = top_gate[t*2 + k];
    }
  }
}

// ---------------- GEMM1: h = relu(gather(x) @ W1[e] + b1[e]) ----------------
__global__ __launch_bounds__(256) void k_gemm1(
    const unsigned short* __restrict__ xb, const unsigned short* __restrict__ w1t,
    const float* __restrict__ b1, const int* __restrict__ slot_token,
    const int* __restrict__ offs, unsigned short* __restrict__ h) {
  __shared__ unsigned short As[2][BM*BK];
  __shared__ unsigned short Bs[2][BN*BK];
  int w = xcd_chunk(blockIdx.x, NMB*NBN1);
  int bm = w / NBN1, bn = w % NBN1;
  int tid = threadIdx.x, wid = tid >> 6, lane = tid & 63;
  int s0 = bm * BM;
  int e = 0;
  #pragma unroll
  for (int i = 1; i < NEXP; ++i) if (s0 >= offs[i]) e = i;

  int tokA[4];
  #pragma unroll
  for (int i = 0; i < 4; ++i) {
    int r = (i*4 + wid)*8 + (lane >> 3);
    int t = slot_token[s0 + r];
    tokA[i] = t < 0 ? 0 : t;
  }
  // T2 swizzle: physical slot (lane&7) of row r holds logical col slot (lane&7)^(r&7);
  // r&7 == lane>>3 here, so the swizzled source column is lane-only.
  int kcs = ((lane & 7) ^ (lane >> 3)) * 8;     // swizzled global col (elements)
  int ldst = (lane & 7) * 8;                    // linear LDS col (elements)
  const unsigned short* w1te = w1t + ((size_t)e*HID + (size_t)bn*BN) * DIM;

  f32x4 acc[4][4];
  #pragma unroll
  for (int m=0;m<4;m++)
    #pragma unroll
    for (int n=0;n<4;n++) acc[m][n] = (f32x4){0.f,0.f,0.f,0.f};

  int wr = wid >> 1, wc = wid & 1;
  int xr = (lane & 7) * 8;                      // read-side XOR term: (row&7)*8

  #define STAGE1(buf, kt) {                                                    \
    int k0_ = (kt)*BK;                                                         \
    _Pragma("unroll")                                                          \
    for (int i = 0; i < 4; ++i) {                                              \
      int r_ = (i*4 + wid)*8 + (lane >> 3);                                    \
      gload_lds16(xb + (size_t)tokA[i]*DIM + k0_ + kcs, &As[buf][r_*BK + ldst]); \
      gload_lds16(w1te + (size_t)r_*DIM + k0_ + kcs, &Bs[buf][r_*BK + ldst]);  \
    } }

  STAGE1(0, 0);
  asm volatile("s_waitcnt vmcnt(0)" ::: "memory");
  __builtin_amdgcn_s_barrier();
  __builtin_amdgcn_sched_barrier(0);

  int cur = 0;
  for (int kt = 0; kt < DIM/BK; ++kt) {
    if (kt + 1 < DIM/BK) STAGE1(cur^1, kt+1);
    #pragma unroll
    for (int ks = 0; ks < 2; ++ks) {
      int kk = (ks*32 + (lane >> 4)*8) ^ xr;    // physical (swizzled) col
      bf16x8 a[4], b[4];
      #pragma unroll
      for (int m=0;m<4;m++) a[m] = *(const bf16x8*)&As[cur][(wr*64 + m*16 + (lane&15))*BK + kk];
      #pragma unroll
      for (int n=0;n<4;n++) b[n] = *(const bf16x8*)&Bs[cur][(wc*64 + n*16 + (lane&15))*BK + kk];
      #pragma unroll
      for (int m=0;m<4;m++)
        #pragma unroll
        for (int n=0;n<4;n++)
          acc[m][n] = __builtin_amdgcn_mfma_f32_16x16x32_bf16(a[m], b[n], acc[m][n], 0,0,0);
    }
    __builtin_amdgcn_sched_barrier(0);
    asm volatile("s_waitcnt vmcnt(0)" ::: "memory");
    __builtin_amdgcn_s_barrier();
    __builtin_amdgcn_sched_barrier(0);
    cur ^= 1;
  }
  #undef STAGE1

  #pragma unroll
  for (int m=0;m<4;m++){
    int row0 = wr*64 + m*16 + (lane>>4)*4;
    #pragma unroll
    for (int n=0;n<4;n++){
      int col = bn*BN + wc*64 + n*16 + (lane&15);
      float bias = b1[e*HID + col];
      #pragma unroll
      for (int r=0;r<4;r++){
        float v = acc[m][n][r] + bias;
        v = v > 0.f ? v : 0.f;
        h[(size_t)(s0 + row0 + r)*HID + col] = f2bf(v);
      }
    }
  }
}

// ---------------- GEMM2: out[tok] += gate * (h @ W2[e] + b2[e]) ----------------
__global__ __launch_bounds__(256) void k_gemm2(
    const unsigned short* __restrict__ h, const unsigned short* __restrict__ w2t,
    const float* __restrict__ b2, const int* __restrict__ slot_token,
    const float* __restrict__ slot_gate, const int* __restrict__ offs,
    float* __restrict__ out) {
  __shared__ unsigned short As[2][BM*BK];
  __shared__ unsigned short Bs[2][BN*BK];
  int w = xcd_chunk(blockIdx.x, NMB*NBN2);
  int bm = w / NBN2, bn = w % NBN2;
  int tid = threadIdx.x, wid = tid >> 6, lane = tid & 63;
  int s0 = bm * BM;
  int e = 0;
  #pragma unroll
  for (int i = 1; i < NEXP; ++i) if (s0 >= offs[i]) e = i;
  int kcs = ((lane & 7) ^ (lane >> 3)) * 8;
  int ldst = (lane & 7) * 8;
  const unsigned short* w2te = w2t + ((size_t)e*DIM + (size_t)bn*BN) * HID;

  f32x4 acc[4][4];
  #pragma unroll
  for (int m=0;m<4;m++)
    #pragma unroll
    for (int n=0;n<4;n++) acc[m][n] = (f32x4){0.f,0.f,0.f,0.f};

  int wr = wid >> 1, wc = wid & 1;
  int xr = (lane & 7) * 8;

  #define STAGE2(buf, kt) {                                                    \
    int k0_ = (kt)*BK;                                                         \
    _Pragma("unroll")                                                          \
    for (int i = 0; i < 4; ++i) {                                              \
      int r_ = (i*4 + wid)*8 + (lane >> 3);                                    \
      gload_lds16(h + (size_t)(s0 + r_)*HID + k0_ + kcs, &As[buf][r_*BK + ldst]); \
      gload_lds16(w2te + (size_t)r_*HID + k0_ + kcs, &Bs[buf][r_*BK + ldst]);  \
    } }

  STAGE2(0, 0);
  asm volatile("s_waitcnt vmcnt(0)" ::: "memory");
  __builtin_amdgcn_s_barrier();
  __builtin_amdgcn_sched_barrier(0);

  int cur = 0;
  for (int kt = 0; kt < HID/BK; ++kt) {
    if (kt + 1 < HID/BK) STAGE2(cur^1, kt+1);
    #pragma unroll
    for (int ks = 0; ks < 2; ++ks) {
      int kk = (ks*32 + (lane >> 4)*8) ^ xr;
      bf16x8 a[4], b[4];
      #pragma unroll
      for (int m=0;m<4;m++) a[m] = *(const bf16x8*)&As[cur][(wr*64 + m*16 + (lane&15))*BK + kk];
      #pragma unroll
      for (int n=0;n<4;n++) b[n] = *(const bf16x8*)&Bs[cur][(wc*64 + n*16 + (lane&15))*BK + kk];
      #pragma unroll
      for (int m=0;m<4;m++)
        #pragma unroll
        for (int n=0;n<4;n++)
          acc[m][n] = __builtin_amdgcn_mfma_f32_16x16x32_bf16(a[m], b[n], acc[m][n], 0,0,0);
    }
    __builtin_amdgcn_sched_barrier(0);
    asm volatile("s_waitcnt vmcnt(0)" ::: "memory");
    __builtin_amdgcn_s_barrier();
    __builtin_amdgcn_sched_barrier(0);
    cur ^= 1;
  }
  #undef STAGE2

  #pragma unroll
  for (int m=0;m<4;m++){
    int rb_ = s0 + wr*64 + m*16 + (lane>>4)*4;
    #pragma unroll
    for (int r=0;r<4;r++){
      int slot = rb_ + r;
      int tok = slot_token[slot];
      if (tok < 0) continue;
      float g = slot_gate[slot];
      #pragma unroll
      for (int n=0;n<4;n++){
        int col = bn*BN + wc*64 + n*16 + (lane&15);
        float v = (acc[m][n][r] + b2[e*DIM + col]) * g;
        atomicAdd(&out[(size_t)tok*DIM + col], v);  // exactly 2 adds/elem -> deterministic
      }
    }
  }
}

extern "C" void kernel_launch(void* const* d_in, const int* in_sizes, int n_in,
                              void* d_out, int out_size, void* d_ws, size_t ws_size,
                              hipStream_t stream) {
  const float* x   = (const float*)d_in[0];
  const float* noi = (const float*)d_in[1];
  const float* Wr  = (const float*)d_in[2];
  const float* br  = (const float*)d_in[3];
  const float* Wn  = (const float*)d_in[4];
  const float* bnb = (const float*)d_in[5];
  const float* W1  = (const float*)d_in[6];
  const float* b1  = (const float*)d_in[7];
  const float* W2  = (const float*)d_in[8];
  const float* b2  = (const float*)d_in[9];
  float* out = (float*)d_out;
  (void)in_sizes; (void)n_in; (void)ws_size;

  char* ws = (char*)d_ws;
  size_t off = 0;
  auto alloc = [&](size_t bytes) -> void* {
    void* p = ws + off; off += (bytes + 255) & ~(size_t)255; return p;
  };
  unsigned short* w1t  = (unsigned short*)alloc((size_t)NEXP*HID*DIM*2);
  unsigned short* w2t  = (unsigned short*)alloc((size_t)NEXP*DIM*HID*2);
  unsigned short* xb   = (unsigned short*)alloc((size_t)N_TOK*DIM*2);
  unsigned short* hbuf = (unsigned short*)alloc((size_t)MAXSLOT*HID*2);
  float* wrt = (float*)alloc(NEXP*DIM*4);
  float* wnt = (float*)alloc(NEXP*DIM*4);
  int*   top_idx  = (int*)alloc(N_TOK*2*4);
  float* top_gate = (float*)alloc(N_TOK*2*4);
  int*   slot_token = (int*)alloc((size_t)MAXSLOT*4);
  float* slot_gate  = (float*)alloc((size_t)MAXSLOT*4);
  int*   ctrl = (int*)alloc(64*4);
  int* counts  = ctrl;        // [10]
  int* cursors = ctrl + 10;   // [10]
  int* offs    = ctrl + 20;   // [11]

  hipMemsetAsync(out, 0, (size_t)out_size*4, stream);
  hipMemsetAsync(ctrl, 0, 64*4, stream);
  hipMemsetAsync(slot_token, 0xFF, (size_t)MAXSLOT*4, stream);  // -1 fill

  k_cvt_x<<<(N_TOK*DIM/8)/256, 256, 0, stream>>>(x, xb);
  k_cvt_router_w<<<(NEXP*DIM+255)/256, 256, 0, stream>>>(Wr, Wn, wrt, wnt);
  k_transpose<<<NEXP*(DIM/64)*(HID/64), 256, 0, stream>>>(W1, w1t, DIM, HID);
  k_transpose<<<NEXP*(HID/64)*(DIM/64), 256, 0, stream>>>(W2, w2t, HID, DIM);
  k_router2<<<N_TOK/RT_TOK, 256, 0, stream>>>(x, noi, wrt, wnt, br, bnb, top_idx, top_gate, counts);
  k_offsets<<<1, 64, 0, stream>>>(counts, cursors, offs);
  k_scatter<<<(N_TOK+255)/256, 256, 0, stream>>>(top_idx, top_gate, cursors, slot_token, slot_gate);
  k_gemm1<<<NMB*NBN1, 256, 0, stream>>>(xb, w1t, b1, slot_token, offs, hbuf);
  k_gemm2<<<NMB*NBN2, 256, 0, stream>>>(hbuf, w2t, b2, slot_token, slot_gate, offs, out);
}